// Round 7
// baseline (297.653 us; speedup 1.0000x reference)
//
#include <hip/hip_runtime.h>
#include <cstddef>

#define B_ 4
#define C_ 512
#define L_ 2048

typedef __attribute__((ext_vector_type(8))) short  short8;   // 8 bf16 (4 VGPRs)
typedef __attribute__((ext_vector_type(4))) float  f32x4;
typedef __attribute__((ext_vector_type(4))) unsigned short us4;

__device__ __forceinline__ float clip10(float v){ return fminf(fmaxf(v,-10.0f),10.0f); }

// round-to-nearest-even fp32 -> bf16 (finite inputs only; ours are clipped)
__device__ __forceinline__ unsigned short f2bf(float f){
  union { float f; unsigned u; } v; v.f = f;
  unsigned r = v.u + 0x7fffu + ((v.u >> 16) & 1u);
  return (unsigned short)(r >> 16);
}
// truncation-pack two fp32 -> bf16x2 in ONE v_perm_b32 (lo -> low half)
__device__ __forceinline__ unsigned pk_tr(float lo, float hi){
  return __builtin_amdgcn_perm(__float_as_uint(hi), __float_as_uint(lo), 0x07060302u);
}

// ---------------------------------------------------------------------------
// Prep (merged): blocks 0..4095 transpose x -> xT bf16; 4096..5119 convert W.
// ---------------------------------------------------------------------------
__global__ __launch_bounds__(256) void prep_k(
    const float* __restrict__ x, const float* __restrict__ Wq,
    const float* __restrict__ Wp, unsigned short* __restrict__ xT,
    unsigned short* __restrict__ Wqb, unsigned short* __restrict__ Wpb)
{
  const int blk = blockIdx.x;
  const int t = threadIdx.x;
  if (blk < 4096){
    __shared__ float tile[32][33];
    const int b = blk>>10, rem = blk&1023;
    const int c0 = (rem>>6)*32, l0 = (rem&63)*32;
    const int cr = t>>3, lc = (t&7)*4;
    const float4 v = *(const float4*)(x + ((size_t)b*C_ + c0+cr)*L_ + l0 + lc);
    tile[cr][lc]=v.x; tile[cr][lc+1]=v.y; tile[cr][lc+2]=v.z; tile[cr][lc+3]=v.w;
    __syncthreads();
    const int lr = t>>3, cc = (t&7)*4;
    const us4 o = { f2bf(tile[cc][lr]), f2bf(tile[cc+1][lr]),
                    f2bf(tile[cc+2][lr]), f2bf(tile[cc+3][lr]) };
    *(us4*)(xT + ((size_t)b*L_ + l0+lr)*C_ + c0 + cc) = o;
  } else {
    const int i = (blk-4096)*256 + t;       // float4 index
    const int NQ = 1536*512/4;
    const float* src; unsigned short* dst; int j;
    if (i < NQ){ src = Wq; dst = Wqb; j = i; }
    else       { src = Wp; dst = Wpb; j = i - NQ; }
    const float4 v = *(const float4*)(src + (size_t)j*4);
    const us4 o = { f2bf(v.x), f2bf(v.y), f2bf(v.z), f2bf(v.w) };
    *(us4*)(dst + (size_t)j*4) = o;
  }
}

// ---------------------------------------------------------------------------
// bf16 MFMA GEMM, BARRIER-FREE: both operands read directly from global as
// b128 fragments (16B/lane, 4 q4-lanes = one full 64B line). No LDS.
// 128x128 tile, K=512 in 16 k-steps of 32.
// MODE 0 (QKV): +bias, clip; q scaled by 0.125*log2e; q/k stored bf16
//               [b][l][512]; v stored bf16 [b][512][l].
// MODE 1 (proj): +bias, fp32 natural [b][512][l].
// ---------------------------------------------------------------------------
template<int MODE>
__global__ __launch_bounds__(256) void mfma_gemm(
    const unsigned short* __restrict__ Wb, const unsigned short* __restrict__ Bin,
    const float* __restrict__ bias,
    unsigned short* __restrict__ qT, unsigned short* __restrict__ kT,
    unsigned short* __restrict__ vN, float* __restrict__ yout)
{
  const int t = threadIdx.x;
  const int b = blockIdx.z;
  const int mb = blockIdx.y, n0 = blockIdx.x*128, m0 = mb*128;
  const int lane = t&63, w = t>>6, wm = w>>1, wn = w&1;
  const int n = lane&15, q4 = lane>>4;

  f32x4 acc[4][4];
#pragma unroll
  for (int i=0;i<4;i++)
#pragma unroll
    for (int j=0;j<4;j++) acc[i][j] = (f32x4){0.f,0.f,0.f,0.f};

  const unsigned short* Ap[4];
  const unsigned short* Bp[4];
#pragma unroll
  for (int mt=0;mt<4;mt++)
    Ap[mt] = Wb + (size_t)(m0 + wm*64 + mt*16 + n)*512 + q4*8;
#pragma unroll
  for (int nt=0;nt<4;nt++)
    Bp[nt] = Bin + ((size_t)b*L_ + n0 + wn*64 + nt*16 + n)*512 + q4*8;

#pragma unroll 4
  for (int k0=0;k0<512;k0+=32){
    short8 aF[4], bF[4];
#pragma unroll
    for (int mt=0;mt<4;mt++) aF[mt] = *(const short8*)(Ap[mt] + k0);
#pragma unroll
    for (int nt=0;nt<4;nt++) bF[nt] = *(const short8*)(Bp[nt] + k0);
#pragma unroll
    for (int mt=0;mt<4;mt++)
#pragma unroll
      for (int nt=0;nt<4;nt++)
        acc[mt][nt] = __builtin_amdgcn_mfma_f32_16x16x32_bf16(aF[mt], bF[nt], acc[mt][nt], 0,0,0);
  }

  // ---- epilogue: C row = m (quad*4+reg), col = n (lane&15)
  const float QS = 0.180336880f;   // 0.125 * log2(e), folded into q
#pragma unroll
  for (int mt=0;mt<4;mt++){
    const int obase = m0 + wm*64 + mt*16 + q4*4;
    const float b0=bias[obase], b1=bias[obase+1], b2=bias[obase+2], b3=bias[obase+3];
#pragma unroll
    for (int nt=0;nt<4;nt++){
      const int l = n0 + wn*64 + nt*16 + n;
      float r0=acc[mt][nt][0]+b0, r1=acc[mt][nt][1]+b1,
            r2=acc[mt][nt][2]+b2, r3=acc[mt][nt][3]+b3;
      if (MODE==0){
        r0=clip10(r0); r1=clip10(r1); r2=clip10(r2); r3=clip10(r3);
        const int typ = mb>>2;                     // 0=q 1=k 2=v
        const int oin = obase - typ*512;
        if (typ < 2){
          if (typ==0){ r0*=QS; r1*=QS; r2*=QS; r3*=QS; }
          unsigned short* dst = (typ==0) ? qT : kT;
          const us4 o = { f2bf(r0), f2bf(r1), f2bf(r2), f2bf(r3) };
          *(us4*)&dst[((size_t)b*L_ + l)*512 + oin] = o;   // [l][c], 8B store
        } else {
          unsigned short* dst = vN + ((size_t)b*512 + oin)*L_ + l;
          dst[0]=f2bf(r0); dst[(size_t)L_]=f2bf(r1);
          dst[(size_t)2*L_]=f2bf(r2); dst[(size_t)3*L_]=f2bf(r3);
        }
      } else {
        float* dst = yout + ((size_t)b*512 + obase)*L_ + l;
        dst[0]=r0; dst[(size_t)L_]=r1; dst[(size_t)2*L_]=r2; dst[(size_t)3*L_]=r3;
      }
    }
  }
}

// ---------------------------------------------------------------------------
// MFMA attention v5: ZERO barriers, no K/V LDS. 128-i tile, wave = 32 i.
// Q B-frags hoisted from global; K A-frags + V B-frags streamed from global
// per j-tile (b128, 64B-line aligned, L1/L2-served). Only P round-trips LDS
// (wave-private rows). q arrives pre-scaled by 0.125*log2e.
// ---------------------------------------------------------------------------
#define PP 72   // s_p pitch in bf16: 144B rows, 16B-aligned

__global__ __launch_bounds__(256) void attn_v5(
    const unsigned short* __restrict__ qT, const unsigned short* __restrict__ kT,
    const unsigned short* __restrict__ vN, unsigned short* __restrict__ attnT)
{
  __shared__ unsigned short s_p[128*PP];   // 18 KB, wave-private rows
  const int t  = threadIdx.x;
  const int i0 = blockIdx.x*128;
  const int h  = blockIdx.y, b = blockIdx.z;
  const int lane = t&63, w = t>>6, n = lane&15, q4 = lane>>4;

  const unsigned short* kb0 = kT + (size_t)b*L_*512 + h*64 + q4*8;
  const unsigned short* vb  = vN + ((size_t)b*512 + h*64)*L_ + q4*8;

  // ---- Q B-fragments, loop-invariant
  short8 qf[2][2];
#pragma unroll
  for (int mt=0; mt<2; mt++)
#pragma unroll
    for (int kk=0; kk<2; kk++)
      qf[mt][kk] = *(const short8*)(qT + ((size_t)b*L_ + i0 + w*32 + mt*16 + n)*512
                                       + h*64 + kk*32 + q4*8);

  // ---- per-jt / per-dt row base pointers
  const unsigned short* kp[4];
  const unsigned short* vp[4];
#pragma unroll
  for (int jt=0;jt<4;jt++) kp[jt] = kb0 + (size_t)(jt*16 + n)*512;
#pragma unroll
  for (int dt=0;dt<4;dt++) vp[dt] = vb  + (size_t)(dt*16 + n)*L_;

  f32x4 oacc[2][4];
  float dacc[2];
#pragma unroll
  for (int mt=0;mt<2;mt++){ dacc[mt]=0.f;
#pragma unroll
    for (int dt=0;dt<4;dt++) oacc[mt][dt]=(f32x4){0.f,0.f,0.f,0.f}; }

  const float LIM = 14.4269504089f;          // 10*log2(e)

  for (int j0=0; j0<L_; j0+=64){
    // ---- K A-fragments for this j-tile (rows j = j0+jt*16+n)
    short8 aK[2][4];
#pragma unroll
    for (int kk=0;kk<2;kk++)
#pragma unroll
      for (int jt=0;jt<4;jt++)
        aK[kk][jt] = *(const short8*)(kp[jt] + (size_t)j0*512 + kk*32);

    // ---- S^T = K·Q^T : D[j][i]; lane col = i (n), rows j = q4*4+r (+jt*16)
    f32x4 sacc[2][4];   // [mt][jt]
#pragma unroll
    for (int mt=0;mt<2;mt++)
#pragma unroll
      for (int jt=0;jt<4;jt++) sacc[mt][jt]=(f32x4){0.f,0.f,0.f,0.f};
#pragma unroll
    for (int kk=0;kk<2;kk++)
#pragma unroll
      for (int mt=0;mt<2;mt++)
#pragma unroll
        for (int jt=0;jt<4;jt++)
          sacc[mt][jt] = __builtin_amdgcn_mfma_f32_16x16x32_bf16(aK[kk][jt], qf[mt][kk], sacc[mt][jt], 0,0,0);

    // ---- V B-fragments (issued here; consumed after exp -> latency hidden)
    short8 bV[2][4];
#pragma unroll
    for (int kk=0;kk<2;kk++)
#pragma unroll
      for (int dt=0;dt<4;dt++)
        bV[kk][dt] = *(const short8*)(vp[dt] + j0 + kk*32);

    // ---- p = exp2(clamp(s)); den += p; trunc-pack -> wave-private P rows
#pragma unroll
    for (int mt=0;mt<2;mt++)
#pragma unroll
      for (int jt=0;jt<4;jt++){
        const float e0 = __builtin_amdgcn_exp2f(__builtin_amdgcn_fmed3f(sacc[mt][jt][0],-LIM,LIM));
        const float e1 = __builtin_amdgcn_exp2f(__builtin_amdgcn_fmed3f(sacc[mt][jt][1],-LIM,LIM));
        const float e2 = __builtin_amdgcn_exp2f(__builtin_amdgcn_fmed3f(sacc[mt][jt][2],-LIM,LIM));
        const float e3 = __builtin_amdgcn_exp2f(__builtin_amdgcn_fmed3f(sacc[mt][jt][3],-LIM,LIM));
        dacc[mt] += (e0+e1)+(e2+e3);
        const unsigned long long pv =
            (unsigned long long)pk_tr(e0,e1) | ((unsigned long long)pk_tr(e2,e3)<<32);
        *(unsigned long long*)&s_p[(w*32 + mt*16 + n)*PP + jt*16 + q4*4] = pv;
      }
    // no barrier anywhere: P rows are written & read by the same wave only

    // ---- O += P·V^T : A = P rows (LDS), B = V frags (regs)
#pragma unroll
    for (int kk=0;kk<2;kk++){
      short8 pA[2];
#pragma unroll
      for (int mt=0;mt<2;mt++)
        pA[mt] = *(const short8*)&s_p[(w*32 + mt*16 + n)*PP + kk*32 + q4*8];
#pragma unroll
      for (int mt=0;mt<2;mt++)
#pragma unroll
        for (int dt=0;dt<4;dt++)
          oacc[mt][dt] = __builtin_amdgcn_mfma_f32_16x16x32_bf16(pA[mt], bV[kk][dt], oacc[mt][dt], 0,0,0);
    }
  }

  // ---- denominator: dacc[mt] = partial for row i = mt*16+n over this q4's j
  float inv[2];
#pragma unroll
  for (int mt=0;mt<2;mt++){
    float d = dacc[mt];
    d += __shfl_xor(d, 16);
    d += __shfl_xor(d, 32);
    inv[mt] = 1.0f/d;
  }
  // output rows are i = mt*16 + q4*4 + r -> their inv lives at lane q4*4+r
  float invr[2][4];
#pragma unroll
  for (int mt=0;mt<2;mt++)
#pragma unroll
    for (int r=0;r<4;r++)
      invr[mt][r] = __shfl(inv[mt], q4*4 + r);

  // ---- store bf16 [b][l][c]: l = i0+w*32+mt*16+q4*4+r, c = h*64+dt*16+n
#pragma unroll
  for (int mt=0;mt<2;mt++)
#pragma unroll
    for (int dt=0;dt<4;dt++)
#pragma unroll
      for (int r=0;r<4;r++){
        const size_t off = ((size_t)b*L_ + i0 + w*32 + mt*16 + q4*4 + r)*512 + h*64 + dt*16 + n;
        attnT[off] = f2bf(oacc[mt][dt][r]*invr[mt][r]);
      }
}

// ---------------------------------------------------------------------------
// GroupNorm split: stats (512 blocks, quarter-group each) + apply.
// Group = 16 ch x 2048 L of (y + x). part[blk] = {sum, sumsq}.
// ---------------------------------------------------------------------------
__global__ __launch_bounds__(256) void gn_stats(
    const float* __restrict__ y, const float* __restrict__ x,
    float* __restrict__ part)
{
  const int blk = blockIdx.x;               // (b<<7)|(g<<2)|s
  const int b = blk>>7, g = (blk>>2)&31, s = blk&3;
  const size_t base = ((size_t)b*C_ + g*16)*L_ + s*512;
  const int t = threadIdx.x;
  float sum=0.f, sq=0.f;
#pragma unroll
  for (int i=0;i<8;i++){
    const int e = i*256 + t;                // 16 rows x 128 float4
    const size_t off = base + (size_t)(e>>7)*L_ + (e&127)*4;
    const float4 vy=*(const float4*)(y+off);
    const float4 vx=*(const float4*)(x+off);
    const float a=vy.x+vx.x, c=vy.y+vx.y, d=vy.z+vx.z, f=vy.w+vx.w;
    sum += (a+c)+(d+f);
    sq  += (a*a+c*c)+(d*d+f*f);
  }
  for (int off=32;off>0;off>>=1){
    sum += __shfl_down(sum,off);
    sq  += __shfl_down(sq,off);
  }
  __shared__ float red[8];
  if ((t&63)==0){ red[(t>>6)*2]=sum; red[(t>>6)*2+1]=sq; }
  __syncthreads();
  if (t==0){
    part[blk*2+0] = red[0]+red[2]+red[4]+red[6];
    part[blk*2+1] = red[1]+red[3]+red[5]+red[7];
  }
}

__global__ __launch_bounds__(256) void gn_apply(
    const float* __restrict__ y, const float* __restrict__ x,
    const float* __restrict__ part,
    const float* __restrict__ gamma, const float* __restrict__ beta,
    float* __restrict__ out)
{
  const int blk = blockIdx.x;
  const int b = blk>>7, g = (blk>>2)&31, s = blk&3;
  const int bg8 = (blk & ~3)*2;
  const float sum = (part[bg8+0]+part[bg8+2])+(part[bg8+4]+part[bg8+6]);
  const float sq  = (part[bg8+1]+part[bg8+3])+(part[bg8+5]+part[bg8+7]);
  const float mu = sum*(1.0f/32768.0f);
  const float rs = rsqrtf(sq*(1.0f/32768.0f) - mu*mu + 1e-5f);
  const size_t base = ((size_t)b*C_ + g*16)*L_ + s*512;
  const int t = threadIdx.x;
#pragma unroll
  for (int i=0;i<8;i++){
    const int e = i*256 + t;
    const int row = e>>7;
    const size_t off = base + (size_t)row*L_ + (e&127)*4;
    const int c = g*16 + row;
    const float ga = gamma[c], be = beta[c];
    const float4 vy=*(const float4*)(y+off);
    const float4 vx=*(const float4*)(x+off);
    float4 r;
    r.x=((vy.x+vx.x)-mu)*rs*ga+be;
    r.y=((vy.y+vx.y)-mu)*rs*ga+be;
    r.z=((vy.z+vx.z)-mu)*rs*ga+be;
    r.w=((vy.w+vx.w)-mu)*rs*ga+be;
    *(float4*)(out+off)=r;
  }
}

// ---------------------------------------------------------------------------
extern "C" void kernel_launch(void* const* d_in, const int* in_sizes, int n_in,
                              void* d_out, int out_size, void* d_ws, size_t ws_size,
                              hipStream_t stream)
{
  (void)in_sizes; (void)n_in; (void)out_size; (void)ws_size;
  const float* x     = (const float*)d_in[0];
  const float* Wqkv  = (const float*)d_in[1];
  const float* bqkv  = (const float*)d_in[2];
  const float* Wproj = (const float*)d_in[3];
  const float* bproj = (const float*)d_in[4];
  const float* gamma = (const float*)d_in[5];
  const float* beta  = (const float*)d_in[6];
  float* out = (float*)d_out;
  char* ws = (char*)d_ws;

  const size_t MB = 1024*1024;
  unsigned short* qT    = (unsigned short*)(ws);            //  8 MB [b][l][512] (pre-scaled)
  unsigned short* kT    = (unsigned short*)(ws +  8*MB);    //  8 MB [b][l][512]
  unsigned short* vN    = (unsigned short*)(ws + 16*MB);    //  8 MB [b][512][l]
  unsigned short* attnT = (unsigned short*)(ws + 24*MB);    //  8 MB [b][l][512]
  unsigned short* xT    = (unsigned short*)(ws + 32*MB);    //  8 MB [b][l][512]
  unsigned short* Wqb   = (unsigned short*)(ws + 40*MB);    // 1.5 MB
  unsigned short* Wpb   = (unsigned short*)(ws + 42*MB);    // 0.5 MB
  float*          y     = (float*)        (ws + 43*MB);     // 16 MB [b][512][l]
  float*          part  = (float*)        (ws + 59*MB);     // 4 KB

  prep_k      <<<dim3(5120),   256,0,stream>>>(x, Wqkv, Wproj, xT, Wqb, Wpb);
  mfma_gemm<0><<<dim3(16,12,4),256,0,stream>>>(Wqb, xT,    bqkv , qT,kT,vN, nullptr);
  attn_v5     <<<dim3(16,8,4), 256,0,stream>>>(qT, kT, vN, attnT);
  mfma_gemm<1><<<dim3(16, 4,4),256,0,stream>>>(Wpb, attnT, bproj, nullptr,nullptr,nullptr, y);
  gn_stats    <<<dim3(512),    256,0,stream>>>(y, x, part);
  gn_apply    <<<dim3(512),    256,0,stream>>>(y, x, part, gamma, beta, out);
}

// Round 8
// 190.481 us; speedup vs baseline: 1.5626x; 1.5626x over previous
//
#include <hip/hip_runtime.h>
#include <cstddef>

#define B_ 4
#define C_ 512
#define L_ 2048

typedef __attribute__((ext_vector_type(8))) short  short8;   // 8 bf16 (4 VGPRs)
typedef __attribute__((ext_vector_type(4))) float  f32x4;
typedef __attribute__((ext_vector_type(4))) unsigned short us4;

#define AS1 __attribute__((address_space(1)))
#define AS3 __attribute__((address_space(3)))

__device__ __forceinline__ float clip10(float v){ return fminf(fmaxf(v,-10.0f),10.0f); }

// round-to-nearest-even fp32 -> bf16 (finite inputs only; ours are clipped)
__device__ __forceinline__ unsigned short f2bf(float f){
  union { float f; unsigned u; } v; v.f = f;
  unsigned r = v.u + 0x7fffu + ((v.u >> 16) & 1u);
  return (unsigned short)(r >> 16);
}
// truncation-pack two fp32 -> bf16x2 in ONE v_perm_b32 (lo -> low half)
__device__ __forceinline__ unsigned pk_tr(float lo, float hi){
  return __builtin_amdgcn_perm(__float_as_uint(hi), __float_as_uint(lo), 0x07060302u);
}
__device__ __forceinline__ float bf2f(unsigned short u){
  return __uint_as_float(((unsigned)u)<<16);
}
// async 16B global -> LDS (direct-to-shared DMA)
__device__ __forceinline__ void gl16(const void* g, void* l){
  __builtin_amdgcn_global_load_lds((const AS1 unsigned*)g, (AS3 unsigned*)l, 16, 0, 0);
}

// ---------------------------------------------------------------------------
// Prep (merged): blocks 0..4095 transpose x -> xT bf16; 4096..5119 convert W.
// ---------------------------------------------------------------------------
__global__ __launch_bounds__(256) void prep_k(
    const float* __restrict__ x, const float* __restrict__ Wq,
    const float* __restrict__ Wp, unsigned short* __restrict__ xT,
    unsigned short* __restrict__ Wqb, unsigned short* __restrict__ Wpb)
{
  const int blk = blockIdx.x;
  const int t = threadIdx.x;
  if (blk < 4096){
    __shared__ float tile[32][33];
    const int b = blk>>10, rem = blk&1023;
    const int c0 = (rem>>6)*32, l0 = (rem&63)*32;
    const int cr = t>>3, lc = (t&7)*4;
    const float4 v = *(const float4*)(x + ((size_t)b*C_ + c0+cr)*L_ + l0 + lc);
    tile[cr][lc]=v.x; tile[cr][lc+1]=v.y; tile[cr][lc+2]=v.z; tile[cr][lc+3]=v.w;
    __syncthreads();
    const int lr = t>>3, cc = (t&7)*4;
    const us4 o = { f2bf(tile[cc][lr]), f2bf(tile[cc+1][lr]),
                    f2bf(tile[cc+2][lr]), f2bf(tile[cc+3][lr]) };
    *(us4*)(xT + ((size_t)b*L_ + l0+lr)*C_ + c0 + cc) = o;
  } else {
    const int i = (blk-4096)*256 + t;       // float4 index
    const int NQ = 1536*512/4;
    const float* src; unsigned short* dst; int j;
    if (i < NQ){ src = Wq; dst = Wqb; j = i; }
    else       { src = Wp; dst = Wpb; j = i - NQ; }
    const float4 v = *(const float4*)(src + (size_t)j*4);
    const us4 o = { f2bf(v.x), f2bf(v.y), f2bf(v.z), f2bf(v.w) };
    *(us4*)(dst + (size_t)j*4) = o;
  }
}

// ---------------------------------------------------------------------------
// bf16 MFMA GEMM (R6 proven LDS-DMA version), 128x128 tile, BK=64, K=512.
// LDS chunks XOR-swizzled: physical chunk = logical ^ (row&7).
// MODE 0 (QKV): +bias, clip; q scaled by 0.125*log2e; q/k bf16 [b][l][512];
//               v bf16 [b][512][l].
// MODE 1 (proj): +bias, fp32 natural [b][512][l].
// ---------------------------------------------------------------------------
template<int MODE>
__global__ __launch_bounds__(256) void mfma_gemm(
    const unsigned short* __restrict__ Wb, const unsigned short* __restrict__ Bin,
    const float* __restrict__ bias,
    unsigned short* __restrict__ qT, unsigned short* __restrict__ kT,
    unsigned short* __restrict__ vN, float* __restrict__ yout)
{
  __shared__ unsigned short SA[128*64];   // [m][k'] bf16, 16KB
  __shared__ unsigned short SB[128*64];   // [n][k'] bf16, 16KB
  const int t = threadIdx.x;
  const int b = blockIdx.z;
  const int mb = blockIdx.y, n0 = blockIdx.x*128, m0 = mb*128;
  const int lane = t&63, w = t>>6, wm = w>>1, wn = w&1;
  const int n = lane&15, q4 = lane>>4;

  f32x4 acc[4][4];
#pragma unroll
  for (int i=0;i<4;i++)
#pragma unroll
    for (int j=0;j<4;j++) acc[i][j] = (f32x4){0.f,0.f,0.f,0.f};

  const unsigned short* Arow = Wb + (size_t)m0*512;
  const unsigned short* Brow = Bin + ((size_t)b*L_ + n0)*512;

  for (int kt=0; kt<8; kt++){
    const int k0 = kt*64;
    __syncthreads();                     // prev-iter fragment reads done
#pragma unroll
    for (int i=0;i<4;i++){
      const int ch = t + 256*i;          // 0..1023 : row=ch>>3, phys chunk=ch&7
      const int row = ch>>3, lc = (ch&7) ^ (row&7);
      gl16(Arow + (size_t)row*512 + k0 + lc*8, &SA[ch*8]);
      gl16(Brow + (size_t)row*512 + k0 + lc*8, &SB[ch*8]);
    }
    __syncthreads();                     // vmcnt(0) drained by compiler
#pragma unroll
    for (int kk=0;kk<2;kk++){
      short8 aF[4], bF[4];
      const int pc = ((kk*4+q4) ^ (n&7))*8;
#pragma unroll
      for (int mt=0;mt<4;mt++) aF[mt] = *(const short8*)&SA[(wm*64+mt*16+n)*64 + pc];
#pragma unroll
      for (int nt=0;nt<4;nt++) bF[nt] = *(const short8*)&SB[(wn*64+nt*16+n)*64 + pc];
#pragma unroll
      for (int mt=0;mt<4;mt++)
#pragma unroll
        for (int nt=0;nt<4;nt++)
          acc[mt][nt] = __builtin_amdgcn_mfma_f32_16x16x32_bf16(aF[mt], bF[nt], acc[mt][nt], 0,0,0);
    }
  }

  // ---- epilogue: C row = m (quad*4+reg), col = n (lane&15)
  const float QS = 0.180336880f;   // 0.125 * log2(e), folded into q
#pragma unroll
  for (int mt=0;mt<4;mt++){
    const int obase = m0 + wm*64 + mt*16 + q4*4;
    const float b0=bias[obase], b1=bias[obase+1], b2=bias[obase+2], b3=bias[obase+3];
#pragma unroll
    for (int nt=0;nt<4;nt++){
      const int l = n0 + wn*64 + nt*16 + n;
      float r0=acc[mt][nt][0]+b0, r1=acc[mt][nt][1]+b1,
            r2=acc[mt][nt][2]+b2, r3=acc[mt][nt][3]+b3;
      if (MODE==0){
        r0=clip10(r0); r1=clip10(r1); r2=clip10(r2); r3=clip10(r3);
        const int typ = mb>>2;                     // 0=q 1=k 2=v
        const int oin = obase - typ*512;
        if (typ < 2){
          if (typ==0){ r0*=QS; r1*=QS; r2*=QS; r3*=QS; }
          unsigned short* dst = (typ==0) ? qT : kT;
          const us4 o = { f2bf(r0), f2bf(r1), f2bf(r2), f2bf(r3) };
          *(us4*)&dst[((size_t)b*L_ + l)*512 + oin] = o;   // [l][c], 8B store
        } else {
          unsigned short* dst = vN + ((size_t)b*512 + oin)*L_ + l;
          dst[0]=f2bf(r0); dst[(size_t)L_]=f2bf(r1);
          dst[(size_t)2*L_]=f2bf(r2); dst[(size_t)3*L_]=f2bf(r3);
        }
      } else {
        float* dst = yout + ((size_t)b*512 + obase)*L_ + l;
        dst[0]=r0; dst[(size_t)L_]=r1; dst[(size_t)2*L_]=r2; dst[(size_t)3*L_]=r3;
      }
    }
  }
}

// ---------------------------------------------------------------------------
// MFMA attention v8: 128-i tile, wave = 32 i, j-SPLIT x2 (each block does
// 1024 j), grid 1024 = 4 blocks/CU. v2's proven DMA staging + 2 barriers.
// S^T = K*Q^T (q pre-scaled by 0.125*log2e) -> exp2 -> pk_tr -> b64 P writes
// (wave-private rows, no barrier) -> PV. Outputs UNNORMALIZED bf16 partials
// + fp32 denominator partials; attn_combine merges halves (linear softmax:
// clip => no max subtraction => partials just add).
// ---------------------------------------------------------------------------
#define PP 72   // s_p pitch in bf16: 144B rows, 16B-aligned, 2-way banks max

__global__ __launch_bounds__(256,4) void attn_v8(
    const unsigned short* __restrict__ qT, const unsigned short* __restrict__ kT,
    const unsigned short* __restrict__ vN,
    unsigned short* __restrict__ Opart, float* __restrict__ den)
{
  __shared__ unsigned short s_k[64*64];    // [j][d] 8KB
  __shared__ unsigned short s_v[64*64];    // [d][j] 8KB
  __shared__ unsigned short s_p[128*PP];   // 18KB, wave-private rows
  const int t  = threadIdx.x;
  const int io = blockIdx.x>>1, half = blockIdx.x&1;
  const int i0 = io*128;
  const int h  = blockIdx.y, b = blockIdx.z;
  const int lane = t&63, w = t>>6, n = lane&15, q4 = lane>>4;
  const int idx = ((b*8+h)*16+io)*2 + half;

  const unsigned short* kb0 = kT + (size_t)b*L_*512 + h*64;
  const unsigned short* vb  = vN + ((size_t)b*512 + h*64)*L_;

  // ---- Q B-fragments, hoisted once from global (one-time divergence)
  short8 qf[2][2];
#pragma unroll
  for (int mt=0; mt<2; mt++)
#pragma unroll
    for (int kk=0; kk<2; kk++)
      qf[mt][kk] = *(const short8*)(qT + ((size_t)b*L_ + i0 + w*32 + mt*16 + n)*512
                                       + h*64 + kk*32 + q4*8);

  f32x4 oacc[2][4];
  float dacc[2];
#pragma unroll
  for (int mt=0;mt<2;mt++){ dacc[mt]=0.f;
#pragma unroll
    for (int dt=0;dt<4;dt++) oacc[mt][dt]=(f32x4){0.f,0.f,0.f,0.f}; }

  const float LIM = 14.4269504089f;          // 10*log2(e)
  const int jbeg = half*1024, jend = jbeg+1024;

  for (int j0=jbeg; j0<jend; j0+=64){
    __syncthreads();                         // prev-iter s_k/s_v reads done
#pragma unroll
    for (int i=0;i<2;i++){
      const int ch = t + 256*i, row = ch>>3, lc = (ch&7)^(row&7);
      gl16(kb0 + (size_t)(j0+row)*512 + lc*8, &s_k[ch*8]);   // K rows j, k=d
      gl16(vb  + (size_t)row*L_ + j0 + lc*8,  &s_v[ch*8]);   // V rows d, k=j
    }
    __syncthreads();                         // DMA drained (vmcnt0 @ barrier)

    // ---- S^T = K*Q^T : D[j][i]; lane col = i (n), rows j = q4*4+r (+jt*16)
    f32x4 sacc[2][4];   // [mt][jt]
#pragma unroll
    for (int mt=0;mt<2;mt++)
#pragma unroll
      for (int jt=0;jt<4;jt++) sacc[mt][jt]=(f32x4){0.f,0.f,0.f,0.f};
#pragma unroll
    for (int kk=0;kk<2;kk++){
      const int pc = ((kk*4+q4) ^ (n&7))*8;
      short8 aK[4];
#pragma unroll
      for (int jt=0;jt<4;jt++) aK[jt] = *(const short8*)&s_k[(jt*16+n)*64 + pc];
#pragma unroll
      for (int mt=0;mt<2;mt++)
#pragma unroll
        for (int jt=0;jt<4;jt++)
          sacc[mt][jt] = __builtin_amdgcn_mfma_f32_16x16x32_bf16(aK[jt], qf[mt][kk], sacc[mt][jt], 0,0,0);
    }

    // ---- p = exp2(clamp(s)); den += p; trunc-pack 4 j -> one b64 write
#pragma unroll
    for (int mt=0;mt<2;mt++)
#pragma unroll
      for (int jt=0;jt<4;jt++){
        const float e0 = __builtin_amdgcn_exp2f(__builtin_amdgcn_fmed3f(sacc[mt][jt][0],-LIM,LIM));
        const float e1 = __builtin_amdgcn_exp2f(__builtin_amdgcn_fmed3f(sacc[mt][jt][1],-LIM,LIM));
        const float e2 = __builtin_amdgcn_exp2f(__builtin_amdgcn_fmed3f(sacc[mt][jt][2],-LIM,LIM));
        const float e3 = __builtin_amdgcn_exp2f(__builtin_amdgcn_fmed3f(sacc[mt][jt][3],-LIM,LIM));
        dacc[mt] += (e0+e1)+(e2+e3);
        const unsigned long long pv =
            (unsigned long long)pk_tr(e0,e1) | ((unsigned long long)pk_tr(e2,e3)<<32);
        *(unsigned long long*)&s_p[(w*32 + mt*16 + n)*PP + jt*16 + q4*4] = pv;
      }
    // no barrier: P rows are written & read by the same wave only

    // ---- O += P*V^T : A = P rows (LDS), B = V frags
#pragma unroll
    for (int kk=0;kk<2;kk++){
      const int pcv = ((kk*4+q4) ^ (n&7))*8;
      short8 bV[4], pA[2];
#pragma unroll
      for (int dt=0;dt<4;dt++) bV[dt] = *(const short8*)&s_v[(dt*16+n)*64 + pcv];
#pragma unroll
      for (int mt=0;mt<2;mt++)
        pA[mt] = *(const short8*)&s_p[(w*32 + mt*16 + n)*PP + kk*32 + q4*8];
#pragma unroll
      for (int mt=0;mt<2;mt++)
#pragma unroll
        for (int dt=0;dt<4;dt++)
          oacc[mt][dt] = __builtin_amdgcn_mfma_f32_16x16x32_bf16(pA[mt], bV[kk==0?dt:dt], oacc[mt][dt], 0,0,0);
    }
  }

  // ---- denominator partial: reduce over q4 groups (full for this half)
#pragma unroll
  for (int mt=0;mt<2;mt++){
    float d = dacc[mt];
    d += __shfl_xor(d, 16);
    d += __shfl_xor(d, 32);
    if (q4 == 0) den[(size_t)idx*128 + w*32 + mt*16 + n] = d;
  }

  // ---- store unnormalized O partial bf16: row i = mt*16+q4*4+r (+w*32),
  //      col = dt*16+n  (consecutive n lanes -> contiguous 32B)
#pragma unroll
  for (int mt=0;mt<2;mt++)
#pragma unroll
    for (int dt=0;dt<4;dt++)
#pragma unroll
      for (int r=0;r<4;r++)
        Opart[(size_t)idx*8192 + (w*32 + mt*16 + q4*4 + r)*64 + dt*16 + n]
            = f2bf(oacc[mt][dt][r]);
}

// ---------------------------------------------------------------------------
// Combine the two j-half partials: attnT = (O0+O1)/(d0+d1), bf16 [b][l][512].
// ---------------------------------------------------------------------------
__global__ __launch_bounds__(256) void attn_combine(
    const unsigned short* __restrict__ Opart, const float* __restrict__ den,
    unsigned short* __restrict__ attnT)
{
  __shared__ float s_inv[128];
  const int io = blockIdx.x, h = blockIdx.y, b = blockIdx.z;
  const int t = threadIdx.x;
  const int base = ((b*8+h)*16+io)*2;
  if (t < 128)
    s_inv[t] = 1.0f/(den[(size_t)base*128 + t] + den[(size_t)(base+1)*128 + t]);
  __syncthreads();
  const unsigned short* O0 = Opart + (size_t)base*8192;
  const unsigned short* O1 = O0 + 8192;
#pragma unroll
  for (int it=0; it<8; it++){
    const int chunk = it*256 + t;           // 2048 chunks of 4 elems
    const int i = chunk>>4, c4 = (chunk&15)*4;
    const us4 a = *(const us4*)&O0[i*64 + c4];
    const us4 c = *(const us4*)&O1[i*64 + c4];
    const float inv = s_inv[i];
    const us4 o = { f2bf((bf2f(a[0])+bf2f(c[0]))*inv),
                    f2bf((bf2f(a[1])+bf2f(c[1]))*inv),
                    f2bf((bf2f(a[2])+bf2f(c[2]))*inv),
                    f2bf((bf2f(a[3])+bf2f(c[3]))*inv) };
    *(us4*)&attnT[((size_t)b*L_ + io*128 + i)*512 + h*64 + c4] = o;
  }
}

// ---------------------------------------------------------------------------
// GroupNorm split: stats (512 blocks, quarter-group each) + apply.
// ---------------------------------------------------------------------------
__global__ __launch_bounds__(256) void gn_stats(
    const float* __restrict__ y, const float* __restrict__ x,
    float* __restrict__ part)
{
  const int blk = blockIdx.x;               // (b<<7)|(g<<2)|s
  const int b = blk>>7, g = (blk>>2)&31, s = blk&3;
  const size_t base = ((size_t)b*C_ + g*16)*L_ + s*512;
  const int t = threadIdx.x;
  float sum=0.f, sq=0.f;
#pragma unroll
  for (int i=0;i<8;i++){
    const int e = i*256 + t;                // 16 rows x 128 float4
    const size_t off = base + (size_t)(e>>7)*L_ + (e&127)*4;
    const float4 vy=*(const float4*)(y+off);
    const float4 vx=*(const float4*)(x+off);
    const float a=vy.x+vx.x, c=vy.y+vx.y, d=vy.z+vx.z, f=vy.w+vx.w;
    sum += (a+c)+(d+f);
    sq  += (a*a+c*c)+(d*d+f*f);
  }
  for (int off=32;off>0;off>>=1){
    sum += __shfl_down(sum,off);
    sq  += __shfl_down(sq,off);
  }
  __shared__ float red[8];
  if ((t&63)==0){ red[(t>>6)*2]=sum; red[(t>>6)*2+1]=sq; }
  __syncthreads();
  if (t==0){
    part[blk*2+0] = red[0]+red[2]+red[4]+red[6];
    part[blk*2+1] = red[1]+red[3]+red[5]+red[7];
  }
}

__global__ __launch_bounds__(256) void gn_apply(
    const float* __restrict__ y, const float* __restrict__ x,
    const float* __restrict__ part,
    const float* __restrict__ gamma, const float* __restrict__ beta,
    float* __restrict__ out)
{
  const int blk = blockIdx.x;
  const int b = blk>>7, g = (blk>>2)&31, s = blk&3;
  const int bg8 = (blk & ~3)*2;
  const float sum = (part[bg8+0]+part[bg8+2])+(part[bg8+4]+part[bg8+6]);
  const float sq  = (part[bg8+1]+part[bg8+3])+(part[bg8+5]+part[bg8+7]);
  const float mu = sum*(1.0f/32768.0f);
  const float rs = rsqrtf(sq*(1.0f/32768.0f) - mu*mu + 1e-5f);
  const size_t base = ((size_t)b*C_ + g*16)*L_ + s*512;
  const int t = threadIdx.x;
#pragma unroll
  for (int i=0;i<8;i++){
    const int e = i*256 + t;
    const int row = e>>7;
    const size_t off = base + (size_t)row*L_ + (e&127)*4;
    const int c = g*16 + row;
    const float ga = gamma[c], be = beta[c];
    const float4 vy=*(const float4*)(y+off);
    const float4 vx=*(const float4*)(x+off);
    float4 r;
    r.x=((vy.x+vx.x)-mu)*rs*ga+be;
    r.y=((vy.y+vx.y)-mu)*rs*ga+be;
    r.z=((vy.z+vx.z)-mu)*rs*ga+be;
    r.w=((vy.w+vx.w)-mu)*rs*ga+be;
    *(float4*)(out+off)=r;
  }
}

// ---------------------------------------------------------------------------
extern "C" void kernel_launch(void* const* d_in, const int* in_sizes, int n_in,
                              void* d_out, int out_size, void* d_ws, size_t ws_size,
                              hipStream_t stream)
{
  (void)in_sizes; (void)n_in; (void)out_size; (void)ws_size;
  const float* x     = (const float*)d_in[0];
  const float* Wqkv  = (const float*)d_in[1];
  const float* bqkv  = (const float*)d_in[2];
  const float* Wproj = (const float*)d_in[3];
  const float* bproj = (const float*)d_in[4];
  const float* gamma = (const float*)d_in[5];
  const float* beta  = (const float*)d_in[6];
  float* out = (float*)d_out;
  char* ws = (char*)d_ws;

  const size_t MB = 1024*1024;
  unsigned short* qT    = (unsigned short*)(ws);            //  8 MB [b][l][512] (pre-scaled)
  unsigned short* kT    = (unsigned short*)(ws +  8*MB);    //  8 MB [b][l][512]
  unsigned short* vN    = (unsigned short*)(ws + 16*MB);    //  8 MB [b][512][l]
  unsigned short* attnT = (unsigned short*)(ws + 24*MB);    //  8 MB [b][l][512]
  unsigned short* xT    = (unsigned short*)(ws + 32*MB);    //  8 MB; dead after QKV gemm
  float*          den   = (float*)        (ws + 32*MB);     // 512 KB (aliases dead xT? NO - see below)
  unsigned short* Wqb   = (unsigned short*)(ws + 40*MB);    // 1.5 MB
  unsigned short* Wpb   = (unsigned short*)(ws + 42*MB);    // 0.5 MB
  float*          y     = (float*)        (ws + 43*MB);     // 16 MB; written AFTER combine
  unsigned short* Opart = (unsigned short*)(ws + 43*MB);    // 16 MB partials (dead before y写)
  float*          part  = (float*)        (ws + 59*MB);     // 4 KB

  // NOTE on aliasing: xT is consumed by mfma_gemm<0> (step 2); den is written
  // by attn_v8 (step 3) and read by attn_combine (step 4) -> safe overlap.
  // Opart lives steps 3-4; y is written by mfma_gemm<1> (step 5) -> safe.

  prep_k      <<<dim3(5120),   256,0,stream>>>(x, Wqkv, Wproj, xT, Wqb, Wpb);
  mfma_gemm<0><<<dim3(16,12,4),256,0,stream>>>(Wqb, xT,    bqkv , qT,kT,vN, nullptr);
  attn_v8     <<<dim3(32,8,4), 256,0,stream>>>(qT, kT, vN, Opart, den);
  attn_combine<<<dim3(16,8,4), 256,0,stream>>>(Opart, den, attnT);
  mfma_gemm<1><<<dim3(16, 4,4),256,0,stream>>>(Wpb, attnT, bproj, nullptr,nullptr,nullptr, y);
  gn_stats    <<<dim3(512),    256,0,stream>>>(y, x, part);
  gn_apply    <<<dim3(512),    256,0,stream>>>(y, x, part, gamma, beta, out);
}

// Round 9
// 189.010 us; speedup vs baseline: 1.5748x; 1.0078x over previous
//
#include <hip/hip_runtime.h>
#include <cstddef>

#define B_ 4
#define C_ 512
#define L_ 2048

typedef __attribute__((ext_vector_type(8))) short  short8;   // 8 bf16 (4 VGPRs)
typedef __attribute__((ext_vector_type(4))) float  f32x4;
typedef __attribute__((ext_vector_type(4))) unsigned short us4;

#define AS1 __attribute__((address_space(1)))
#define AS3 __attribute__((address_space(3)))

__device__ __forceinline__ float clip10(float v){ return fminf(fmaxf(v,-10.0f),10.0f); }

// round-to-nearest-even fp32 -> bf16 (finite inputs only; ours are clipped)
__device__ __forceinline__ unsigned short f2bf(float f){
  union { float f; unsigned u; } v; v.f = f;
  unsigned r = v.u + 0x7fffu + ((v.u >> 16) & 1u);
  return (unsigned short)(r >> 16);
}
// truncation-pack two fp32 -> bf16x2 in ONE v_perm_b32 (lo -> low half)
__device__ __forceinline__ unsigned pk_tr(float lo, float hi){
  return __builtin_amdgcn_perm(__float_as_uint(hi), __float_as_uint(lo), 0x07060302u);
}
__device__ __forceinline__ float bf2f(unsigned short u){
  return __uint_as_float(((unsigned)u)<<16);
}
// async 16B global -> LDS (direct-to-shared DMA)
__device__ __forceinline__ void gl16(const void* g, void* l){
  __builtin_amdgcn_global_load_lds((const AS1 unsigned*)g, (AS3 unsigned*)l, 16, 0, 0);
}

// ---------------------------------------------------------------------------
// Prep: blocks 0..4095 transpose x -> xT bf16; 4096..5119 convert W;
// block 5120 zeroes the groupnorm partial accumulators (re-poison-safe).
// ---------------------------------------------------------------------------
__global__ __launch_bounds__(256) void prep_k(
    const float* __restrict__ x, const float* __restrict__ Wq,
    const float* __restrict__ Wp, unsigned short* __restrict__ xT,
    unsigned short* __restrict__ Wqb, unsigned short* __restrict__ Wpb,
    float* __restrict__ part)
{
  const int blk = blockIdx.x;
  const int t = threadIdx.x;
  if (blk < 4096){
    __shared__ float tile[32][33];
    const int b = blk>>10, rem = blk&1023;
    const int c0 = (rem>>6)*32, l0 = (rem&63)*32;
    const int cr = t>>3, lc = (t&7)*4;
    const float4 v = *(const float4*)(x + ((size_t)b*C_ + c0+cr)*L_ + l0 + lc);
    tile[cr][lc]=v.x; tile[cr][lc+1]=v.y; tile[cr][lc+2]=v.z; tile[cr][lc+3]=v.w;
    __syncthreads();
    const int lr = t>>3, cc = (t&7)*4;
    const us4 o = { f2bf(tile[cc][lr]), f2bf(tile[cc+1][lr]),
                    f2bf(tile[cc+2][lr]), f2bf(tile[cc+3][lr]) };
    *(us4*)(xT + ((size_t)b*L_ + l0+lr)*C_ + c0 + cc) = o;
  } else if (blk < 5120){
    const int i = (blk-4096)*256 + t;       // float4 index
    const int NQ = 1536*512/4;
    const float* src; unsigned short* dst; int j;
    if (i < NQ){ src = Wq; dst = Wqb; j = i; }
    else       { src = Wp; dst = Wpb; j = i - NQ; }
    const float4 v = *(const float4*)(src + (size_t)j*4);
    const us4 o = { f2bf(v.x), f2bf(v.y), f2bf(v.z), f2bf(v.w) };
    *(us4*)(dst + (size_t)j*4) = o;
  } else {
    part[t] = 0.f;                          // 4 batches x 32 groups x {sum,sq}
  }
}

// ---------------------------------------------------------------------------
// bf16 MFMA GEMM (LDS-DMA), 128x128 tile, BK=64, K=512.
// LDS chunks XOR-swizzled: physical chunk = logical ^ (row&7).
// MODE 0 (QKV): +bias, clip; q scaled by 0.125*log2e; q/k bf16 [b][l][512];
//               v bf16 [b][512][l].
// MODE 1 (proj): +bias +x residual -> y fp32 [b][512][l]; per-group (16ch)
//               sum/sumsq wave-reduced and atomicAdd'ed into part[b][g].
// ---------------------------------------------------------------------------
template<int MODE>
__global__ __launch_bounds__(256) void mfma_gemm(
    const unsigned short* __restrict__ Wb, const unsigned short* __restrict__ Bin,
    const float* __restrict__ bias, const float* __restrict__ xres,
    unsigned short* __restrict__ qT, unsigned short* __restrict__ kT,
    unsigned short* __restrict__ vN, float* __restrict__ yout,
    float* __restrict__ part)
{
  __shared__ unsigned short SA[128*64];   // [m][k'] bf16, 16KB
  __shared__ unsigned short SB[128*64];   // [n][k'] bf16, 16KB
  const int t = threadIdx.x;
  const int b = blockIdx.z;
  const int mb = blockIdx.y, n0 = blockIdx.x*128, m0 = mb*128;
  const int lane = t&63, w = t>>6, wm = w>>1, wn = w&1;
  const int n = lane&15, q4 = lane>>4;

  f32x4 acc[4][4];
#pragma unroll
  for (int i=0;i<4;i++)
#pragma unroll
    for (int j=0;j<4;j++) acc[i][j] = (f32x4){0.f,0.f,0.f,0.f};

  const unsigned short* Arow = Wb + (size_t)m0*512;
  const unsigned short* Brow = Bin + ((size_t)b*L_ + n0)*512;

  for (int kt=0; kt<8; kt++){
    const int k0 = kt*64;
    __syncthreads();                     // prev-iter fragment reads done
#pragma unroll
    for (int i=0;i<4;i++){
      const int ch = t + 256*i;          // 0..1023 : row=ch>>3, phys chunk=ch&7
      const int row = ch>>3, lc = (ch&7) ^ (row&7);
      gl16(Arow + (size_t)row*512 + k0 + lc*8, &SA[ch*8]);
      gl16(Brow + (size_t)row*512 + k0 + lc*8, &SB[ch*8]);
    }
    __syncthreads();                     // vmcnt(0) drained by compiler
#pragma unroll
    for (int kk=0;kk<2;kk++){
      short8 aF[4], bF[4];
      const int pc = ((kk*4+q4) ^ (n&7))*8;
#pragma unroll
      for (int mt=0;mt<4;mt++) aF[mt] = *(const short8*)&SA[(wm*64+mt*16+n)*64 + pc];
#pragma unroll
      for (int nt=0;nt<4;nt++) bF[nt] = *(const short8*)&SB[(wn*64+nt*16+n)*64 + pc];
#pragma unroll
      for (int mt=0;mt<4;mt++)
#pragma unroll
        for (int nt=0;nt<4;nt++)
          acc[mt][nt] = __builtin_amdgcn_mfma_f32_16x16x32_bf16(aF[mt], bF[nt], acc[mt][nt], 0,0,0);
    }
  }

  // ---- epilogue: C row = m (quad*4+reg), col = n (lane&15)
  const float QS = 0.180336880f;   // 0.125 * log2(e), folded into q
#pragma unroll
  for (int mt=0;mt<4;mt++){
    const int obase = m0 + wm*64 + mt*16 + q4*4;
    const float b0=bias[obase], b1=bias[obase+1], b2=bias[obase+2], b3=bias[obase+3];
    float gs=0.f, gq=0.f;
#pragma unroll
    for (int nt=0;nt<4;nt++){
      const int l = n0 + wn*64 + nt*16 + n;
      float r0=acc[mt][nt][0]+b0, r1=acc[mt][nt][1]+b1,
            r2=acc[mt][nt][2]+b2, r3=acc[mt][nt][3]+b3;
      if (MODE==0){
        r0=clip10(r0); r1=clip10(r1); r2=clip10(r2); r3=clip10(r3);
        const int typ = mb>>2;                     // 0=q 1=k 2=v
        const int oin = obase - typ*512;
        if (typ < 2){
          if (typ==0){ r0*=QS; r1*=QS; r2*=QS; r3*=QS; }
          unsigned short* dst = (typ==0) ? qT : kT;
          const us4 o = { f2bf(r0), f2bf(r1), f2bf(r2), f2bf(r3) };
          *(us4*)&dst[((size_t)b*L_ + l)*512 + oin] = o;   // [l][c], 8B store
        } else {
          unsigned short* dst = vN + ((size_t)b*512 + oin)*L_ + l;
          dst[0]=f2bf(r0); dst[(size_t)L_]=f2bf(r1);
          dst[(size_t)2*L_]=f2bf(r2); dst[(size_t)3*L_]=f2bf(r3);
        }
      } else {
        const float* xp = xres + ((size_t)b*512 + obase)*L_ + l;
        const float y0=r0+xp[0], y1=r1+xp[(size_t)L_],
                    y2=r2+xp[(size_t)2*L_], y3=r3+xp[(size_t)3*L_];
        float* dst = yout + ((size_t)b*512 + obase)*L_ + l;
        dst[0]=y0; dst[(size_t)L_]=y1; dst[(size_t)2*L_]=y2; dst[(size_t)3*L_]=y3;
        gs += (y0+y1)+(y2+y3);
        gq += (y0*y0+y1*y1)+(y2*y2+y3*y3);
      }
    }
    if (MODE==1){
      // whole wave belongs to one 16-channel group for this mt
#pragma unroll
      for (int off=1; off<64; off<<=1){
        gs += __shfl_xor(gs, off);
        gq += __shfl_xor(gq, off);
      }
      if (lane==0){
        const int g = mb*8 + wm*4 + mt;
        atomicAdd(&part[(b*32+g)*2+0], gs);
        atomicAdd(&part[(b*32+g)*2+1], gq);
      }
    }
  }
}

// ---------------------------------------------------------------------------
// MFMA attention v9: v8 (128-i tile, j-split x2, grid 1024 = 4 blocks/CU,
// DMA staging, wave-private bf16 P) + denominator via ones-column MFMA:
// den = P*1 accumulates in C-layout alongside O — no VALU adds, no shuffles.
// Outputs unnormalized bf16 O partials + fp32 den partials.
// ---------------------------------------------------------------------------
#define PP 72   // s_p pitch in bf16: 144B rows, 16B-aligned, 2-way banks max

__global__ __launch_bounds__(256,4) void attn_v9(
    const unsigned short* __restrict__ qT, const unsigned short* __restrict__ kT,
    const unsigned short* __restrict__ vN,
    unsigned short* __restrict__ Opart, float* __restrict__ den)
{
  __shared__ unsigned short s_k[64*64];    // [j][d] 8KB
  __shared__ unsigned short s_v[64*64];    // [d][j] 8KB
  __shared__ unsigned short s_p[128*PP];   // 18KB, wave-private rows
  const int t  = threadIdx.x;
  const int io = blockIdx.x>>1, half = blockIdx.x&1;
  const int i0 = io*128;
  const int h  = blockIdx.y, b = blockIdx.z;
  const int lane = t&63, w = t>>6, n = lane&15, q4 = lane>>4;
  const int idx = ((b*8+h)*16+io)*2 + half;

  const unsigned short* kb0 = kT + (size_t)b*L_*512 + h*64;
  const unsigned short* vb  = vN + ((size_t)b*512 + h*64)*L_;

  // ---- Q B-fragments, hoisted once from global (one-time divergence)
  short8 qf[2][2];
#pragma unroll
  for (int mt=0; mt<2; mt++)
#pragma unroll
    for (int kk=0; kk<2; kk++)
      qf[mt][kk] = *(const short8*)(qT + ((size_t)b*L_ + i0 + w*32 + mt*16 + n)*512
                                       + h*64 + kk*32 + q4*8);

  // ---- all-ones bf16 B-fragment for the denominator MFMA
  short8 ones;
#pragma unroll
  for (int i=0;i<8;i++) ones[i] = (short)0x3F80;

  f32x4 oacc[2][4];
  f32x4 oden[2];
#pragma unroll
  for (int mt=0;mt<2;mt++){ oden[mt]=(f32x4){0.f,0.f,0.f,0.f};
#pragma unroll
    for (int dt=0;dt<4;dt++) oacc[mt][dt]=(f32x4){0.f,0.f,0.f,0.f}; }

  const float LIM = 14.4269504089f;          // 10*log2(e)
  const int jbeg = half*1024, jend = jbeg+1024;

  for (int j0=jbeg; j0<jend; j0+=64){
    __syncthreads();                         // prev-iter s_k/s_v reads done
#pragma unroll
    for (int i=0;i<2;i++){
      const int ch = t + 256*i, row = ch>>3, lc = (ch&7)^(row&7);
      gl16(kb0 + (size_t)(j0+row)*512 + lc*8, &s_k[ch*8]);   // K rows j, k=d
      gl16(vb  + (size_t)row*L_ + j0 + lc*8,  &s_v[ch*8]);   // V rows d, k=j
    }
    __syncthreads();                         // DMA drained (vmcnt0 @ barrier)

    // ---- S^T = K*Q^T : D[j][i]; lane col = i (n), rows j = q4*4+r (+jt*16)
    f32x4 sacc[2][4];   // [mt][jt]
#pragma unroll
    for (int mt=0;mt<2;mt++)
#pragma unroll
      for (int jt=0;jt<4;jt++) sacc[mt][jt]=(f32x4){0.f,0.f,0.f,0.f};
#pragma unroll
    for (int kk=0;kk<2;kk++){
      const int pc = ((kk*4+q4) ^ (n&7))*8;
      short8 aK[4];
#pragma unroll
      for (int jt=0;jt<4;jt++) aK[jt] = *(const short8*)&s_k[(jt*16+n)*64 + pc];
#pragma unroll
      for (int mt=0;mt<2;mt++)
#pragma unroll
        for (int jt=0;jt<4;jt++)
          sacc[mt][jt] = __builtin_amdgcn_mfma_f32_16x16x32_bf16(aK[jt], qf[mt][kk], sacc[mt][jt], 0,0,0);
    }

    // ---- p = exp2(clamp(s)); trunc-pack 4 consecutive j -> one b64 write
#pragma unroll
    for (int mt=0;mt<2;mt++)
#pragma unroll
      for (int jt=0;jt<4;jt++){
        const float e0 = __builtin_amdgcn_exp2f(__builtin_amdgcn_fmed3f(sacc[mt][jt][0],-LIM,LIM));
        const float e1 = __builtin_amdgcn_exp2f(__builtin_amdgcn_fmed3f(sacc[mt][jt][1],-LIM,LIM));
        const float e2 = __builtin_amdgcn_exp2f(__builtin_amdgcn_fmed3f(sacc[mt][jt][2],-LIM,LIM));
        const float e3 = __builtin_amdgcn_exp2f(__builtin_amdgcn_fmed3f(sacc[mt][jt][3],-LIM,LIM));
        const unsigned long long pv =
            (unsigned long long)pk_tr(e0,e1) | ((unsigned long long)pk_tr(e2,e3)<<32);
        *(unsigned long long*)&s_p[(w*32 + mt*16 + n)*PP + jt*16 + q4*4] = pv;
      }
    // no barrier: P rows are written & read by the same wave only

    // ---- O += P*V^T ; den += P*1 (ones MFMA -> C-layout, no VALU adds)
#pragma unroll
    for (int kk=0;kk<2;kk++){
      const int pcv = ((kk*4+q4) ^ (n&7))*8;
      short8 bV[4], pA[2];
#pragma unroll
      for (int dt=0;dt<4;dt++) bV[dt] = *(const short8*)&s_v[(dt*16+n)*64 + pcv];
#pragma unroll
      for (int mt=0;mt<2;mt++)
        pA[mt] = *(const short8*)&s_p[(w*32 + mt*16 + n)*PP + kk*32 + q4*8];
#pragma unroll
      for (int mt=0;mt<2;mt++){
#pragma unroll
        for (int dt=0;dt<4;dt++)
          oacc[mt][dt] = __builtin_amdgcn_mfma_f32_16x16x32_bf16(pA[mt], bV[dt], oacc[mt][dt], 0,0,0);
        oden[mt] = __builtin_amdgcn_mfma_f32_16x16x32_bf16(pA[mt], ones, oden[mt], 0,0,0);
      }
    }
  }

  // ---- den partial: C-layout rows i = mt*16+q4*4+r, all cols identical
  if (n == 0){
#pragma unroll
    for (int mt=0;mt<2;mt++)
#pragma unroll
      for (int r=0;r<4;r++)
        den[(size_t)idx*128 + w*32 + mt*16 + q4*4 + r] = oden[mt][r];
  }

  // ---- store unnormalized O partial bf16: row i = mt*16+q4*4+r (+w*32),
  //      col = dt*16+n  (consecutive n lanes -> contiguous 32B)
#pragma unroll
  for (int mt=0;mt<2;mt++)
#pragma unroll
    for (int dt=0;dt<4;dt++)
#pragma unroll
      for (int r=0;r<4;r++)
        Opart[(size_t)idx*8192 + (w*32 + mt*16 + q4*4 + r)*64 + dt*16 + n]
            = f2bf(oacc[mt][dt][r]);
}

// ---------------------------------------------------------------------------
// Combine the two j-half partials: attnT = (O0+O1)/(d0+d1), bf16 [b][l][512].
// ---------------------------------------------------------------------------
__global__ __launch_bounds__(256) void attn_combine(
    const unsigned short* __restrict__ Opart, const float* __restrict__ den,
    unsigned short* __restrict__ attnT)
{
  __shared__ float s_inv[128];
  const int io = blockIdx.x, h = blockIdx.y, b = blockIdx.z;
  const int t = threadIdx.x;
  const int base = ((b*8+h)*16+io)*2;
  if (t < 128)
    s_inv[t] = 1.0f/(den[(size_t)base*128 + t] + den[(size_t)(base+1)*128 + t]);
  __syncthreads();
  const unsigned short* O0 = Opart + (size_t)base*8192;
  const unsigned short* O1 = O0 + 8192;
#pragma unroll
  for (int it=0; it<8; it++){
    const int chunk = it*256 + t;           // 2048 chunks of 4 elems
    const int i = chunk>>4, c4 = (chunk&15)*4;
    const us4 a = *(const us4*)&O0[i*64 + c4];
    const us4 c = *(const us4*)&O1[i*64 + c4];
    const float inv = s_inv[i];
    const us4 o = { f2bf((bf2f(a[0])+bf2f(c[0]))*inv),
                    f2bf((bf2f(a[1])+bf2f(c[1]))*inv),
                    f2bf((bf2f(a[2])+bf2f(c[2]))*inv),
                    f2bf((bf2f(a[3])+bf2f(c[3]))*inv) };
    *(us4*)&attnT[((size_t)b*L_ + io*128 + i)*512 + h*64 + c4] = o;
  }
}

// ---------------------------------------------------------------------------
// GroupNorm apply: stats come from mfma_gemm<1>'s fused atomics in part[].
// y already contains proj + bias + x. 512 blocks, quarter-group each.
// ---------------------------------------------------------------------------
__global__ __launch_bounds__(256) void gn_apply(
    const float* __restrict__ y, const float* __restrict__ part,
    const float* __restrict__ gamma, const float* __restrict__ beta,
    float* __restrict__ out)
{
  const int blk = blockIdx.x;
  const int b = blk>>7, g = (blk>>2)&31, s = blk&3;
  const float sum = part[(b*32+g)*2+0];
  const float sq  = part[(b*32+g)*2+1];
  const float mu = sum*(1.0f/32768.0f);
  const float rs = rsqrtf(sq*(1.0f/32768.0f) - mu*mu + 1e-5f);
  const size_t base = ((size_t)b*C_ + g*16)*L_ + s*512;
  const int t = threadIdx.x;
#pragma unroll
  for (int i=0;i<8;i++){
    const int e = i*256 + t;
    const int row = e>>7;
    const size_t off = base + (size_t)row*L_ + (e&127)*4;
    const int c = g*16 + row;
    const float ga = gamma[c], be = beta[c];
    const float4 vy=*(const float4*)(y+off);
    float4 r;
    r.x=(vy.x-mu)*rs*ga+be;
    r.y=(vy.y-mu)*rs*ga+be;
    r.z=(vy.z-mu)*rs*ga+be;
    r.w=(vy.w-mu)*rs*ga+be;
    *(float4*)(out+off)=r;
  }
}

// ---------------------------------------------------------------------------
extern "C" void kernel_launch(void* const* d_in, const int* in_sizes, int n_in,
                              void* d_out, int out_size, void* d_ws, size_t ws_size,
                              hipStream_t stream)
{
  (void)in_sizes; (void)n_in; (void)out_size; (void)ws_size;
  const float* x     = (const float*)d_in[0];
  const float* Wqkv  = (const float*)d_in[1];
  const float* bqkv  = (const float*)d_in[2];
  const float* Wproj = (const float*)d_in[3];
  const float* bproj = (const float*)d_in[4];
  const float* gamma = (const float*)d_in[5];
  const float* beta  = (const float*)d_in[6];
  float* out = (float*)d_out;
  char* ws = (char*)d_ws;

  const size_t MB = 1024*1024;
  unsigned short* qT    = (unsigned short*)(ws);            //  8 MB [b][l][512] (pre-scaled)
  unsigned short* kT    = (unsigned short*)(ws +  8*MB);    //  8 MB [b][l][512]
  unsigned short* vN    = (unsigned short*)(ws + 16*MB);    //  8 MB [b][512][l]
  unsigned short* attnT = (unsigned short*)(ws + 24*MB);    //  8 MB [b][l][512]
  unsigned short* xT    = (unsigned short*)(ws + 32*MB);    //  8 MB; dead after QKV gemm
  float*          den   = (float*)        (ws + 41*MB);     // 512 KB
  unsigned short* Wqb   = (unsigned short*)(ws + 42*MB);    // 1.5 MB
  unsigned short* Wpb   = (unsigned short*)(ws + 44*MB);    // 0.5 MB
  float*          y     = (float*)        (ws + 45*MB);     // 16 MB; written step 5
  unsigned short* Opart = (unsigned short*)(ws + 45*MB);    // 16 MB partials (dead before y)
  float*          part  = (float*)        (ws + 61*MB);     // 1 KB (256 floats)

  prep_k      <<<dim3(5121),   256,0,stream>>>(x, Wqkv, Wproj, xT, Wqb, Wpb, part);
  mfma_gemm<0><<<dim3(16,12,4),256,0,stream>>>(Wqb, xT,    bqkv , nullptr, qT,kT,vN, nullptr, nullptr);
  attn_v9     <<<dim3(32,8,4), 256,0,stream>>>(qT, kT, vN, Opart, den);
  attn_combine<<<dim3(16,8,4), 256,0,stream>>>(Opart, den, attnT);
  mfma_gemm<1><<<dim3(16, 4,4),256,0,stream>>>(Wpb, attnT, bproj, x, nullptr,nullptr,nullptr, y, part);
  gn_apply    <<<dim3(512),    256,0,stream>>>(y, part, gamma, beta, out);
}